// Round 3
// baseline (2178.648 us; speedup 1.0000x reference)
//
#include <hip/hip_runtime.h>

#define N_NODES 50000
#define N_EDGES 800000
#define F_IN 128
#define F_HID 256
#define F_OUT 64

// ---------------- degree / norm ----------------

__global__ void deg_init_kernel(float* __restrict__ deg, int n) {
    int i = blockIdx.x * blockDim.x + threadIdx.x;
    if (i < n) deg[i] = 1.0f;  // self-loop contributes 1
}

__global__ void deg_edges_kernel(const int* __restrict__ cols, float* __restrict__ deg, int e) {
    int i = blockIdx.x * blockDim.x + threadIdx.x;
    if (i < e) atomicAdd(&deg[cols[i]], 1.0f);
}

__global__ void dinv_kernel(float* __restrict__ deg, int n) {
    int i = blockIdx.x * blockDim.x + threadIdx.x;
    if (i < n) deg[i] = rsqrtf(deg[i]);  // deg >= 1 always
}

// ---------------- propagate (segment_sum with symmetric norm) ----------------
// dst[i] = bias + dinv[i]^2 * src[i]  (self loop + bias init)
template <int F>
__global__ void prop_init_kernel(const float* __restrict__ src,
                                 const float* __restrict__ dinv,
                                 const float* __restrict__ bias,
                                 float* __restrict__ dst, int n) {
    const int C = F / 4;
    int idx = blockIdx.x * blockDim.x + threadIdx.x;
    int i = idx / C;
    int f4 = idx % C;
    if (i >= n) return;
    float w = dinv[i];
    w = w * w;
    float4 v = ((const float4*)src)[(size_t)i * C + f4];
    float4 o;
    o.x = v.x * w; o.y = v.y * w; o.z = v.z * w; o.w = v.w * w;
    if (bias) {
        o.x += bias[f4 * 4 + 0];
        o.y += bias[f4 * 4 + 1];
        o.z += bias[f4 * 4 + 2];
        o.w += bias[f4 * 4 + 3];
    }
    ((float4*)dst)[(size_t)i * C + f4] = o;
}

// dst[col[e]] += dinv[row]*dinv[col] * src[row[e]]
template <int F>
__global__ void prop_edge_kernel(const float* __restrict__ src,
                                 const int* __restrict__ rows,
                                 const int* __restrict__ cols,
                                 const float* __restrict__ dinv,
                                 float* __restrict__ dst, int e) {
    const int C = F / 4;
    int idx = blockIdx.x * blockDim.x + threadIdx.x;
    int eid = idx / C;
    int f4 = idx % C;
    if (eid >= e) return;
    int r = rows[eid];
    int c = cols[eid];
    float w = dinv[r] * dinv[c];
    float4 v = ((const float4*)src)[(size_t)r * C + f4];
    float* d = &dst[(size_t)c * F + f4 * 4];
    atomicAdd(d + 0, v.x * w);
    atomicAdd(d + 1, v.y * w);
    atomicAdd(d + 2, v.z * w);
    atomicAdd(d + 3, v.w * w);
}

// ---------------- fp32 GEMM: C[M,N] = A[M,K] @ B[K,N] (+bias, relu) ----------------
// 64x64 tile, BK=8, 256 threads, 4x4 micro-tile per thread.
__global__ __launch_bounds__(256) void gemm64_kernel(const float* __restrict__ A,
                                                     const float* __restrict__ B,
                                                     const float* __restrict__ bias,
                                                     float* __restrict__ C,
                                                     int M, int N, int K, int relu) {
    __shared__ float As[8][64];
    __shared__ float Bs[8][64];
    int tid = threadIdx.x;
    int tx = tid % 16;
    int ty = tid / 16;
    int bm0 = blockIdx.x * 64;
    int bn0 = blockIdx.y * 64;

    // A-load mapping: each thread loads one float2 of the 64x8 A tile
    int am = tid / 4;            // 0..63 (tile row)
    int ak = (tid % 4) * 2;      // 0,2,4,6 (tile k)
    // B-load mapping: each thread loads one float2 of the 8x64 B tile
    int bk = tid / 32;           // 0..7
    int bc = (tid % 32) * 2;     // 0..62

    float acc[4][4] = {};

    for (int k0 = 0; k0 < K; k0 += 8) {
        float2 av;
        if (bm0 + am < M)
            av = *(const float2*)&A[(size_t)(bm0 + am) * K + k0 + ak];
        else
            av = make_float2(0.f, 0.f);
        As[ak][am] = av.x;
        As[ak + 1][am] = av.y;

        float2 bv = *(const float2*)&B[(size_t)(k0 + bk) * N + bn0 + bc];
        Bs[bk][bc] = bv.x;
        Bs[bk][bc + 1] = bv.y;
        __syncthreads();

#pragma unroll
        for (int kk = 0; kk < 8; ++kk) {
            float a[4], b[4];
#pragma unroll
            for (int i = 0; i < 4; ++i) a[i] = As[kk][ty * 4 + i];
#pragma unroll
            for (int j = 0; j < 4; ++j) b[j] = Bs[kk][tx * 4 + j];
#pragma unroll
            for (int i = 0; i < 4; ++i)
#pragma unroll
                for (int j = 0; j < 4; ++j) acc[i][j] = fmaf(a[i], b[j], acc[i][j]);
        }
        __syncthreads();
    }

#pragma unroll
    for (int i = 0; i < 4; ++i) {
        int row = bm0 + ty * 4 + i;
        if (row >= M) continue;
#pragma unroll
        for (int j = 0; j < 4; ++j) {
            int col = bn0 + tx * 4 + j;
            float v = acc[i][j];
            if (bias) v += bias[col];
            if (relu) v = fmaxf(v, 0.f);
            C[(size_t)row * N + col] = v;
        }
    }
}

// ---------------- launch ----------------

extern "C" void kernel_launch(void* const* d_in, const int* in_sizes, int n_in,
                              void* d_out, int out_size, void* d_ws, size_t ws_size,
                              hipStream_t stream) {
    const float* x = (const float*)d_in[0];          // [N, 128]
    const int* edge_index = (const int*)d_in[1];     // [2, E]
    const float* W1 = (const float*)d_in[2];         // [128, 256]
    const float* b1 = (const float*)d_in[3];         // [256]
    const float* W2 = (const float*)d_in[4];         // [256, 64]
    const float* b2 = (const float*)d_in[5];         // [64]
    float* out = (float*)d_out;                      // [N, 64]

    const int* rows = edge_index;                    // source nodes
    const int* cols = edge_index + N_EDGES;          // target nodes

    char* ws = (char*)d_ws;
    float* dinv = (float*)(ws);                                  // 200 KB @ 0
    float* aggx = (float*)(ws + (256ull << 10));                 // 25.6 MB  [N,128] @ 256KB
    float* h1   = (float*)(ws + (26ull << 20) + (256ull << 10)); // 51.2 MB  [N,256]
    float* t2   = aggx;                                          // reuse: [N,64] (12.8 MB)

    const int BT = 256;

    // 1) degrees (with self loops) -> dinv
    deg_init_kernel<<<(N_NODES + BT - 1) / BT, BT, 0, stream>>>(dinv, N_NODES);
    deg_edges_kernel<<<(N_EDGES + BT - 1) / BT, BT, 0, stream>>>(cols, dinv, N_EDGES);
    dinv_kernel<<<(N_NODES + BT - 1) / BT, BT, 0, stream>>>(dinv, N_NODES);

    // 2) layer 1: propagate x (128 feats) first, then GEMM (+b1, relu)
    {
        int total = N_NODES * (F_IN / 4);
        prop_init_kernel<F_IN><<<(total + BT - 1) / BT, BT, 0, stream>>>(x, dinv, nullptr, aggx, N_NODES);
        int etotal = N_EDGES * (F_IN / 4);
        prop_edge_kernel<F_IN><<<(etotal + BT - 1) / BT, BT, 0, stream>>>(x, rows, cols, dinv, aggx, N_EDGES);
        dim3 grid((N_NODES + 63) / 64, F_HID / 64);
        gemm64_kernel<<<grid, 256, 0, stream>>>(aggx, W1, b1, h1, N_NODES, F_HID, F_IN, 1);
    }

    // 3) layer 2: transform first (64 feats), then propagate into out (+b2)
    {
        dim3 grid((N_NODES + 63) / 64, F_OUT / 64);
        gemm64_kernel<<<grid, 256, 0, stream>>>(h1, W2, nullptr, t2, N_NODES, F_OUT, F_HID, 0);
        int total = N_NODES * (F_OUT / 4);
        prop_init_kernel<F_OUT><<<(total + BT - 1) / BT, BT, 0, stream>>>(t2, dinv, b2, out, N_NODES);
        int etotal = N_EDGES * (F_OUT / 4);
        prop_edge_kernel<F_OUT><<<(etotal + BT - 1) / BT, BT, 0, stream>>>(t2, rows, cols, dinv, out, N_EDGES);
    }
}

// Round 7
// 506.592 us; speedup vs baseline: 4.3006x; 4.3006x over previous
//
#include <hip/hip_runtime.h>

#define N_NODES 50000
#define N_EDGES 800000
#define F_IN 128
#define F_HID 256
#define F_OUT 64

// ---------------- workspace layout (bytes) ----------------
// h1      @ 0        : [N,256] f32   (51.2 MB)
// row_ptr @ 49.00 MiB: int[N+1]
// cnt     @ 49.25 MiB: int[N]
// cursor  @ 49.50 MiB: int[N]
// dinv    @ 49.75 MiB: f32[N]
// eidx    @ 50.00 MiB: int[E]        (3.2 MB)
// t2      @ 53.25 MiB: [N,64] f32    (12.8 MB)  -> total ~66.1 MiB

#define OFF_ROWPTR (49ull << 20)
#define OFF_CNT    ((49ull << 20) + (256ull << 10))
#define OFF_CURSOR ((49ull << 20) + (512ull << 10))
#define OFF_DINV   ((49ull << 20) + (768ull << 10))
#define OFF_EIDX   (50ull << 20)
#define OFF_T2     ((53ull << 20) + (256ull << 10))

// ---------------- CSR build ----------------

__global__ void zero_cnt_kernel(int* __restrict__ cnt, int n) {
    int i = blockIdx.x * blockDim.x + threadIdx.x;
    if (i < n) cnt[i] = 0;
}

__global__ void hist_kernel(const int* __restrict__ cols, int* __restrict__ cnt, int e) {
    int i = blockIdx.x * blockDim.x + threadIdx.x;
    if (i < e) atomicAdd(&cnt[cols[i]], 1);
}

__global__ void dinv_kernel(const int* __restrict__ cnt, float* __restrict__ dinv, int n) {
    int i = blockIdx.x * blockDim.x + threadIdx.x;
    if (i < n) dinv[i] = rsqrtf((float)cnt[i] + 1.0f);  // +1 self loop
}

// single-block exclusive scan of cnt -> row_ptr (and cursor copy)
__global__ __launch_bounds__(1024) void scan_kernel(const int* __restrict__ cnt,
                                                    int* __restrict__ row_ptr,
                                                    int* __restrict__ cursor) {
    __shared__ int s[1024];
    const int CH = 49;  // 1024*49 = 50176 >= 50000
    int t = threadIdx.x;
    int base = t * CH;
    int ls = 0;
    for (int i = 0; i < CH; ++i) {
        int idx = base + i;
        if (idx < N_NODES) ls += cnt[idx];
    }
    s[t] = ls;
    __syncthreads();
    for (int off = 1; off < 1024; off <<= 1) {
        int v = (t >= off) ? s[t - off] : 0;
        __syncthreads();
        s[t] += v;
        __syncthreads();
    }
    int run = s[t] - ls;  // exclusive prefix of this chunk
    for (int i = 0; i < CH; ++i) {
        int idx = base + i;
        if (idx < N_NODES) {
            row_ptr[idx] = run;
            cursor[idx] = run;
            run += cnt[idx];
        }
    }
    if (t == 0) row_ptr[N_NODES] = N_EDGES;
}

__global__ void scatter_kernel(const int* __restrict__ rows, const int* __restrict__ cols,
                               int* __restrict__ cursor, int* __restrict__ eidx, int e) {
    int i = blockIdx.x * blockDim.x + threadIdx.x;
    if (i < e) {
        int c = cols[i];
        int pos = atomicAdd(&cursor[c], 1);
        eidx[pos] = rows[i];
    }
}

// ---------------- fused layer 1: gather(x) tile -> LDS -> GEMM W1 (+b1, relu) ----------------
// grid.x = ceil(N/64); block = 256. Output h1[N,256].
__global__ __launch_bounds__(256) void l1_kernel(const float* __restrict__ x,
                                                 const int* __restrict__ row_ptr,
                                                 const int* __restrict__ eidx,
                                                 const float* __restrict__ dinv,
                                                 const float* __restrict__ W1,
                                                 const float* __restrict__ b1,
                                                 float* __restrict__ h1) {
    __shared__ float Ax[F_IN][65];    // transposed gathered A-tile [k][node], padded
    __shared__ float Bs[8][F_HID];    // W1 k-slab
    int tid = threadIdx.x;
    int bm0 = blockIdx.x * 64;

    // ---- gather phase: 32 lanes per node (one float4 column each), 8 nodes/pass ----
    {
        int f4 = tid & 31;   // 0..31 -> feature quad
        int nl0 = tid >> 5;  // 0..7
        for (int p = 0; p < 8; ++p) {
            int nl = nl0 * 8 + p;  // 0..63
            int c = bm0 + nl;
            float4 acc = make_float4(0.f, 0.f, 0.f, 0.f);
            if (c < N_NODES) {
                float dc = dinv[c];
                float4 v = ((const float4*)x)[(size_t)c * 32 + f4];
                acc.x = dc * v.x; acc.y = dc * v.y; acc.z = dc * v.z; acc.w = dc * v.w;
                int k1 = row_ptr[c + 1];
                for (int k = row_ptr[c]; k < k1; ++k) {
                    int r = eidx[k];
                    float w = dinv[r];
                    float4 u = ((const float4*)x)[(size_t)r * 32 + f4];
                    acc.x = fmaf(w, u.x, acc.x);
                    acc.y = fmaf(w, u.y, acc.y);
                    acc.z = fmaf(w, u.z, acc.z);
                    acc.w = fmaf(w, u.w, acc.w);
                }
                acc.x *= dc; acc.y *= dc; acc.z *= dc; acc.w *= dc;
            }
            Ax[f4 * 4 + 0][nl] = acc.x;
            Ax[f4 * 4 + 1][nl] = acc.y;
            Ax[f4 * 4 + 2][nl] = acc.z;
            Ax[f4 * 4 + 3][nl] = acc.w;
        }
    }
    __syncthreads();

    // ---- GEMM phase: C[64x256] = Ax^T(64x128) @ W1(128x256) ----
    int tx = tid & 15;   // 16 col-quads
    int ty = tid >> 4;   // 16 row-groups of 4
    float acc[4][4][4] = {};  // [i][jg][q]: row = ty*4+i, col = jg*64 + tx*4 + q

    for (int k0 = 0; k0 < F_IN; k0 += 8) {
        {   // load W1[k0..k0+7][0:256] -> Bs
            int bk = tid >> 5;  // 0..7
            int c8 = tid & 31;  // 0..31 -> 8 floats
            const float4* src = (const float4*)&W1[(size_t)(k0 + bk) * F_HID + c8 * 8];
            float4 u0 = src[0];
            float4 u1 = src[1];
            ((float4*)&Bs[bk][c8 * 8])[0] = u0;
            ((float4*)&Bs[bk][c8 * 8])[1] = u1;
        }
        __syncthreads();
#pragma unroll
        for (int kk = 0; kk < 8; ++kk) {
            float a[4];
#pragma unroll
            for (int i = 0; i < 4; ++i) a[i] = Ax[k0 + kk][ty * 4 + i];
            float b[4][4];
#pragma unroll
            for (int jg = 0; jg < 4; ++jg) {
                float4 bb = *(const float4*)&Bs[kk][jg * 64 + tx * 4];
                b[jg][0] = bb.x; b[jg][1] = bb.y; b[jg][2] = bb.z; b[jg][3] = bb.w;
            }
#pragma unroll
            for (int i = 0; i < 4; ++i)
#pragma unroll
                for (int jg = 0; jg < 4; ++jg)
#pragma unroll
                    for (int q = 0; q < 4; ++q)
                        acc[i][jg][q] = fmaf(a[i], b[jg][q], acc[i][jg][q]);
        }
        __syncthreads();
    }

    // ---- epilogue: +b1, relu, store ----
#pragma unroll
    for (int i = 0; i < 4; ++i) {
        int row = bm0 + ty * 4 + i;
        if (row >= N_NODES) continue;
#pragma unroll
        for (int jg = 0; jg < 4; ++jg) {
            int col = jg * 64 + tx * 4;
            float4 bias = *(const float4*)&b1[col];
            float4 o;
            o.x = fmaxf(acc[i][jg][0] + bias.x, 0.f);
            o.y = fmaxf(acc[i][jg][1] + bias.y, 0.f);
            o.z = fmaxf(acc[i][jg][2] + bias.z, 0.f);
            o.w = fmaxf(acc[i][jg][3] + bias.w, 0.f);
            *(float4*)&h1[(size_t)row * F_HID + col] = o;
        }
    }
}

// ---------------- fp32 GEMM (layer 2 transform): C[M,N]=A@B ----------------
__global__ __launch_bounds__(256) void gemm64_kernel(const float* __restrict__ A,
                                                     const float* __restrict__ B,
                                                     float* __restrict__ C,
                                                     int M, int N, int K) {
    __shared__ float As[8][64];
    __shared__ float Bs[8][64];
    int tid = threadIdx.x;
    int tx = tid % 16;
    int ty = tid / 16;
    int bm0 = blockIdx.x * 64;
    int bn0 = blockIdx.y * 64;

    int am = tid / 4;
    int ak = (tid % 4) * 2;
    int bk = tid / 32;
    int bc = (tid % 32) * 2;

    float acc[4][4] = {};

    for (int k0 = 0; k0 < K; k0 += 8) {
        float2 av;
        if (bm0 + am < M)
            av = *(const float2*)&A[(size_t)(bm0 + am) * K + k0 + ak];
        else
            av = make_float2(0.f, 0.f);
        As[ak][am] = av.x;
        As[ak + 1][am] = av.y;

        float2 bv = *(const float2*)&B[(size_t)(k0 + bk) * N + bn0 + bc];
        Bs[bk][bc] = bv.x;
        Bs[bk][bc + 1] = bv.y;
        __syncthreads();

#pragma unroll
        for (int kk = 0; kk < 8; ++kk) {
            float a[4], b[4];
#pragma unroll
            for (int i = 0; i < 4; ++i) a[i] = As[kk][ty * 4 + i];
#pragma unroll
            for (int j = 0; j < 4; ++j) b[j] = Bs[kk][tx * 4 + j];
#pragma unroll
            for (int i = 0; i < 4; ++i)
#pragma unroll
                for (int j = 0; j < 4; ++j) acc[i][j] = fmaf(a[i], b[j], acc[i][j]);
        }
        __syncthreads();
    }

#pragma unroll
    for (int i = 0; i < 4; ++i) {
        int row = bm0 + ty * 4 + i;
        if (row >= M) continue;
#pragma unroll
        for (int j = 0; j < 4; ++j) {
            int col = bn0 + tx * 4 + j;
            C[(size_t)row * N + col] = acc[i][j];
        }
    }
}

// ---------------- layer 2 pull-gather: out = A2(t2) + b2 ----------------
// 16 nodes/block, 16 lanes (float4 each) per node.
__global__ __launch_bounds__(256) void l2_gather_kernel(const float* __restrict__ t2,
                                                        const int* __restrict__ row_ptr,
                                                        const int* __restrict__ eidx,
                                                        const float* __restrict__ dinv,
                                                        const float* __restrict__ b2,
                                                        float* __restrict__ out) {
    int tid = threadIdx.x;
    int f4 = tid & 15;   // 0..15 -> feature quad (64 feats)
    int nl = tid >> 4;   // 0..15
    int c = blockIdx.x * 16 + nl;
    if (c >= N_NODES) return;
    float dc = dinv[c];
    float4 v = ((const float4*)t2)[(size_t)c * 16 + f4];
    float4 acc;
    acc.x = dc * v.x; acc.y = dc * v.y; acc.z = dc * v.z; acc.w = dc * v.w;
    int k1 = row_ptr[c + 1];
    for (int k = row_ptr[c]; k < k1; ++k) {
        int r = eidx[k];
        float w = dinv[r];
        float4 u = ((const float4*)t2)[(size_t)r * 16 + f4];
        acc.x = fmaf(w, u.x, acc.x);
        acc.y = fmaf(w, u.y, acc.y);
        acc.z = fmaf(w, u.z, acc.z);
        acc.w = fmaf(w, u.w, acc.w);
    }
    float4 bias = *(const float4*)&b2[f4 * 4];
    float4 o;
    o.x = fmaf(dc, acc.x, bias.x);
    o.y = fmaf(dc, acc.y, bias.y);
    o.z = fmaf(dc, acc.z, bias.z);
    o.w = fmaf(dc, acc.w, bias.w);
    ((float4*)out)[(size_t)c * 16 + f4] = o;
}

// ---------------- launch ----------------

extern "C" void kernel_launch(void* const* d_in, const int* in_sizes, int n_in,
                              void* d_out, int out_size, void* d_ws, size_t ws_size,
                              hipStream_t stream) {
    const float* x = (const float*)d_in[0];
    const int* edge_index = (const int*)d_in[1];
    const float* W1 = (const float*)d_in[2];
    const float* b1 = (const float*)d_in[3];
    const float* W2 = (const float*)d_in[4];
    const float* b2 = (const float*)d_in[5];
    float* out = (float*)d_out;

    const int* rows = edge_index;            // source nodes
    const int* cols = edge_index + N_EDGES;  // target nodes

    char* ws = (char*)d_ws;
    float* h1 = (float*)(ws);
    int* row_ptr = (int*)(ws + OFF_ROWPTR);
    int* cnt = (int*)(ws + OFF_CNT);
    int* cursor = (int*)(ws + OFF_CURSOR);
    float* dinv = (float*)(ws + OFF_DINV);
    int* eidx = (int*)(ws + OFF_EIDX);
    float* t2 = (float*)(ws + OFF_T2);

    const int BT = 256;

    // CSR build + degree norm
    zero_cnt_kernel<<<(N_NODES + BT - 1) / BT, BT, 0, stream>>>(cnt, N_NODES);
    hist_kernel<<<(N_EDGES + BT - 1) / BT, BT, 0, stream>>>(cols, cnt, N_EDGES);
    dinv_kernel<<<(N_NODES + BT - 1) / BT, BT, 0, stream>>>(cnt, dinv, N_NODES);
    scan_kernel<<<1, 1024, 0, stream>>>(cnt, row_ptr, cursor);
    scatter_kernel<<<(N_EDGES + BT - 1) / BT, BT, 0, stream>>>(rows, cols, cursor, eidx, N_EDGES);

    // layer 1: fused gather + GEMM(W1) + bias + relu
    l1_kernel<<<(N_NODES + 63) / 64, 256, 0, stream>>>(x, row_ptr, eidx, dinv, W1, b1, h1);

    // layer 2: transform (h1 @ W2 -> t2), then pull-gather (+b2) into out
    {
        dim3 grid((N_NODES + 63) / 64, F_OUT / 64);
        gemm64_kernel<<<grid, 256, 0, stream>>>(h1, W2, t2, N_NODES, F_OUT, F_HID);
    }
    l2_gather_kernel<<<(N_NODES + 15) / 16, 256, 0, stream>>>(t2, row_ptr, eidx, dinv, b2, out);
}

// Round 8
// 409.961 us; speedup vs baseline: 5.3143x; 1.2357x over previous
//
#include <hip/hip_runtime.h>

#define N_NODES 50000
#define N_EDGES 800000
#define F_IN 128
#define F_HID 256
#define F_OUT 64

// ---------------- workspace layout (bytes) ----------------
// h1      @ 0        : [N,256] f32   (51.2 MB)
// row_ptr @ 49.00 MiB: int[N+1]
// cnt     @ 49.25 MiB: int[N]
// cursor  @ 49.50 MiB: int[N]
// dinv    @ 49.75 MiB: f32[N]
// eidx    @ 50.00 MiB: int[E]        (3.2 MB)
// t2s     @ 53.25 MiB: [N,64] f32    (12.8 MB)  -> total ~66.1 MiB (proven <= ws)

#define OFF_ROWPTR (49ull << 20)
#define OFF_CNT    ((49ull << 20) + (256ull << 10))
#define OFF_CURSOR ((49ull << 20) + (512ull << 10))
#define OFF_DINV   ((49ull << 20) + (768ull << 10))
#define OFF_EIDX   (50ull << 20)
#define OFF_T2     ((53ull << 20) + (256ull << 10))

// ---------------- CSR build ----------------

__global__ void zero_cnt_kernel(int* __restrict__ cnt, int n) {
    int i = blockIdx.x * blockDim.x + threadIdx.x;
    if (i < n) cnt[i] = 0;
}

__global__ void hist_kernel(const int* __restrict__ cols, int* __restrict__ cnt, int e) {
    int i = blockIdx.x * blockDim.x + threadIdx.x;
    if (i < e) atomicAdd(&cnt[cols[i]], 1);
}

__global__ void dinv_kernel(const int* __restrict__ cnt, float* __restrict__ dinv, int n) {
    int i = blockIdx.x * blockDim.x + threadIdx.x;
    if (i < n) dinv[i] = rsqrtf((float)cnt[i] + 1.0f);  // +1 self loop
}

// single-block exclusive scan of cnt -> row_ptr (and cursor copy)
__global__ __launch_bounds__(1024) void scan_kernel(const int* __restrict__ cnt,
                                                    int* __restrict__ row_ptr,
                                                    int* __restrict__ cursor) {
    __shared__ int s[1024];
    const int CH = 49;  // 1024*49 = 50176 >= 50000
    int t = threadIdx.x;
    int base = t * CH;
    int ls = 0;
    for (int i = 0; i < CH; ++i) {
        int idx = base + i;
        if (idx < N_NODES) ls += cnt[idx];
    }
    s[t] = ls;
    __syncthreads();
    for (int off = 1; off < 1024; off <<= 1) {
        int v = (t >= off) ? s[t - off] : 0;
        __syncthreads();
        s[t] += v;
        __syncthreads();
    }
    int run = s[t] - ls;  // exclusive prefix of this chunk
    for (int i = 0; i < CH; ++i) {
        int idx = base + i;
        if (idx < N_NODES) {
            row_ptr[idx] = run;
            cursor[idx] = run;
            run += cnt[idx];
        }
    }
    if (t == 0) row_ptr[N_NODES] = N_EDGES;
}

__global__ void scatter_kernel(const int* __restrict__ rows, const int* __restrict__ cols,
                               int* __restrict__ cursor, int* __restrict__ eidx, int e) {
    int i = blockIdx.x * blockDim.x + threadIdx.x;
    if (i < e) {
        int c = cols[i];
        int pos = atomicAdd(&cursor[c], 1);
        eidx[pos] = rows[i];
    }
}

// ---------------- fused layer 1: gather(x) tile -> LDS -> GEMM W1 (+b1, relu) ----------------
// grid.x = ceil(N/64); block = 256. Output h1[N,256].
// LDS: Ax[64][128] node-major (32 KB) + Bs[8][256] (8 KB) = 40960 B -> 4 blocks/CU.
__global__ __launch_bounds__(256) void l1_kernel(const float* __restrict__ x,
                                                 const int* __restrict__ row_ptr,
                                                 const int* __restrict__ eidx,
                                                 const float* __restrict__ dinv,
                                                 const float* __restrict__ W1,
                                                 const float* __restrict__ b1,
                                                 float* __restrict__ h1) {
    __shared__ float Ax[64][F_IN];    // gathered A-tile, node-major, unpadded
    __shared__ float Bs[8][F_HID];    // W1 k-slab
    int tid = threadIdx.x;
    int bm0 = blockIdx.x * 64;

    // ---- gather phase: 32 lanes per node (one float4 column each), 8 nodes/pass ----
    {
        int f4 = tid & 31;   // 0..31 -> feature quad
        int nl0 = tid >> 5;  // 0..7
        for (int p = 0; p < 8; ++p) {
            int nl = nl0 * 8 + p;  // 0..63
            int c = bm0 + nl;
            float4 acc = make_float4(0.f, 0.f, 0.f, 0.f);
            if (c < N_NODES) {
                float dc = dinv[c];
                float4 v = ((const float4*)x)[(size_t)c * 32 + f4];
                acc.x = dc * v.x; acc.y = dc * v.y; acc.z = dc * v.z; acc.w = dc * v.w;
                int k = row_ptr[c];
                int k1 = row_ptr[c + 1];
                // 4-wide unrolled: 4 independent gather chains in flight
                for (; k + 4 <= k1; k += 4) {
                    int r0 = eidx[k + 0];
                    int r1 = eidx[k + 1];
                    int r2 = eidx[k + 2];
                    int r3 = eidx[k + 3];
                    float w0 = dinv[r0], w1 = dinv[r1], w2 = dinv[r2], w3 = dinv[r3];
                    float4 u0 = ((const float4*)x)[(size_t)r0 * 32 + f4];
                    float4 u1 = ((const float4*)x)[(size_t)r1 * 32 + f4];
                    float4 u2 = ((const float4*)x)[(size_t)r2 * 32 + f4];
                    float4 u3 = ((const float4*)x)[(size_t)r3 * 32 + f4];
                    acc.x = fmaf(w0, u0.x, acc.x); acc.y = fmaf(w0, u0.y, acc.y);
                    acc.z = fmaf(w0, u0.z, acc.z); acc.w = fmaf(w0, u0.w, acc.w);
                    acc.x = fmaf(w1, u1.x, acc.x); acc.y = fmaf(w1, u1.y, acc.y);
                    acc.z = fmaf(w1, u1.z, acc.z); acc.w = fmaf(w1, u1.w, acc.w);
                    acc.x = fmaf(w2, u2.x, acc.x); acc.y = fmaf(w2, u2.y, acc.y);
                    acc.z = fmaf(w2, u2.z, acc.z); acc.w = fmaf(w2, u2.w, acc.w);
                    acc.x = fmaf(w3, u3.x, acc.x); acc.y = fmaf(w3, u3.y, acc.y);
                    acc.z = fmaf(w3, u3.z, acc.z); acc.w = fmaf(w3, u3.w, acc.w);
                }
                for (; k < k1; ++k) {
                    int r = eidx[k];
                    float w = dinv[r];
                    float4 u = ((const float4*)x)[(size_t)r * 32 + f4];
                    acc.x = fmaf(w, u.x, acc.x);
                    acc.y = fmaf(w, u.y, acc.y);
                    acc.z = fmaf(w, u.z, acc.z);
                    acc.w = fmaf(w, u.w, acc.w);
                }
                acc.x *= dc; acc.y *= dc; acc.z *= dc; acc.w *= dc;
            }
            ((float4*)&Ax[nl][0])[f4] = acc;  // contiguous 16B write per lane
        }
    }
    __syncthreads();

    // ---- GEMM phase: C[64x256] = Ax(64x128) @ W1(128x256) ----
    int tx = tid & 15;   // 16 col-quads
    int ty = tid >> 4;   // 16 row-groups of 4
    float acc[4][4][4] = {};  // [i][jg][q]: row = ty*4+i, col = jg*64 + tx*4 + q

    for (int k0 = 0; k0 < F_IN; k0 += 8) {
        {   // load W1[k0..k0+7][0:256] -> Bs
            int bk = tid >> 5;  // 0..7
            int c8 = tid & 31;  // 0..31 -> 8 floats
            const float4* src = (const float4*)&W1[(size_t)(k0 + bk) * F_HID + c8 * 8];
            float4 u0 = src[0];
            float4 u1 = src[1];
            ((float4*)&Bs[bk][c8 * 8])[0] = u0;
            ((float4*)&Bs[bk][c8 * 8])[1] = u1;
        }
        __syncthreads();
#pragma unroll
        for (int kk4 = 0; kk4 < 2; ++kk4) {
            float4 a4[4];
#pragma unroll
            for (int i = 0; i < 4; ++i)
                a4[i] = *(const float4*)&Ax[ty * 4 + i][k0 + kk4 * 4];
#pragma unroll
            for (int q4 = 0; q4 < 4; ++q4) {
                int kk = kk4 * 4 + q4;
                float a[4];
                a[0] = (q4 == 0) ? a4[0].x : (q4 == 1) ? a4[0].y : (q4 == 2) ? a4[0].z : a4[0].w;
                a[1] = (q4 == 0) ? a4[1].x : (q4 == 1) ? a4[1].y : (q4 == 2) ? a4[1].z : a4[1].w;
                a[2] = (q4 == 0) ? a4[2].x : (q4 == 1) ? a4[2].y : (q4 == 2) ? a4[2].z : a4[2].w;
                a[3] = (q4 == 0) ? a4[3].x : (q4 == 1) ? a4[3].y : (q4 == 2) ? a4[3].z : a4[3].w;
                float b[4][4];
#pragma unroll
                for (int jg = 0; jg < 4; ++jg) {
                    float4 bb = *(const float4*)&Bs[kk][jg * 64 + tx * 4];
                    b[jg][0] = bb.x; b[jg][1] = bb.y; b[jg][2] = bb.z; b[jg][3] = bb.w;
                }
#pragma unroll
                for (int i = 0; i < 4; ++i)
#pragma unroll
                    for (int jg = 0; jg < 4; ++jg)
#pragma unroll
                        for (int q = 0; q < 4; ++q)
                            acc[i][jg][q] = fmaf(a[i], b[jg][q], acc[i][jg][q]);
            }
        }
        __syncthreads();
    }

    // ---- epilogue: +b1, relu, store ----
#pragma unroll
    for (int i = 0; i < 4; ++i) {
        int row = bm0 + ty * 4 + i;
        if (row >= N_NODES) continue;
#pragma unroll
        for (int jg = 0; jg < 4; ++jg) {
            int col = jg * 64 + tx * 4;
            float4 bias = *(const float4*)&b1[col];
            float4 o;
            o.x = fmaxf(acc[i][jg][0] + bias.x, 0.f);
            o.y = fmaxf(acc[i][jg][1] + bias.y, 0.f);
            o.z = fmaxf(acc[i][jg][2] + bias.z, 0.f);
            o.w = fmaxf(acc[i][jg][3] + bias.w, 0.f);
            *(float4*)&h1[(size_t)row * F_HID + col] = o;
        }
    }
}

// ---------------- fp32 GEMM (layer 2 transform): t2s[M,N] = dinv[row] * (A@B) ----------------
__global__ __launch_bounds__(256) void gemm64_kernel(const float* __restrict__ A,
                                                     const float* __restrict__ B,
                                                     const float* __restrict__ dinv,
                                                     float* __restrict__ C,
                                                     int M, int N, int K) {
    __shared__ float As[8][64];
    __shared__ float Bs[8][64];
    int tid = threadIdx.x;
    int tx = tid % 16;
    int ty = tid / 16;
    int bm0 = blockIdx.x * 64;
    int bn0 = blockIdx.y * 64;

    int am = tid / 4;
    int ak = (tid % 4) * 2;
    int bk = tid / 32;
    int bc = (tid % 32) * 2;

    float acc[4][4] = {};

    for (int k0 = 0; k0 < K; k0 += 8) {
        float2 av;
        if (bm0 + am < M)
            av = *(const float2*)&A[(size_t)(bm0 + am) * K + k0 + ak];
        else
            av = make_float2(0.f, 0.f);
        As[ak][am] = av.x;
        As[ak + 1][am] = av.y;

        float2 bv = *(const float2*)&B[(size_t)(k0 + bk) * N + bn0 + bc];
        Bs[bk][bc] = bv.x;
        Bs[bk][bc + 1] = bv.y;
        __syncthreads();

#pragma unroll
        for (int kk = 0; kk < 8; ++kk) {
            float a[4], b[4];
#pragma unroll
            for (int i = 0; i < 4; ++i) a[i] = As[kk][ty * 4 + i];
#pragma unroll
            for (int j = 0; j < 4; ++j) b[j] = Bs[kk][tx * 4 + j];
#pragma unroll
            for (int i = 0; i < 4; ++i)
#pragma unroll
                for (int j = 0; j < 4; ++j) acc[i][j] = fmaf(a[i], b[j], acc[i][j]);
        }
        __syncthreads();
    }

#pragma unroll
    for (int i = 0; i < 4; ++i) {
        int row = bm0 + ty * 4 + i;
        if (row >= M) continue;
        float d = dinv[row];
#pragma unroll
        for (int j = 0; j < 4; ++j) {
            int col = bn0 + tx * 4 + j;
            C[(size_t)row * N + col] = d * acc[i][j];
        }
    }
}

// ---------------- layer 2 pull-gather: out = dinv[c]*(t2s[c] + sum t2s[r]) + b2 ----------------
// 16 nodes/block, 16 lanes (float4 each) per node. t2s is pre-scaled by dinv.
__global__ __launch_bounds__(256) void l2_gather_kernel(const float* __restrict__ t2s,
                                                        const int* __restrict__ row_ptr,
                                                        const int* __restrict__ eidx,
                                                        const float* __restrict__ dinv,
                                                        const float* __restrict__ b2,
                                                        float* __restrict__ out) {
    int tid = threadIdx.x;
    int f4 = tid & 15;   // 0..15 -> feature quad (64 feats)
    int nl = tid >> 4;   // 0..15
    int c = blockIdx.x * 16 + nl;
    if (c >= N_NODES) return;
    float4 acc = ((const float4*)t2s)[(size_t)c * 16 + f4];  // self loop (pre-scaled)
    int k = row_ptr[c];
    int k1 = row_ptr[c + 1];
    for (; k + 4 <= k1; k += 4) {
        int r0 = eidx[k + 0];
        int r1 = eidx[k + 1];
        int r2 = eidx[k + 2];
        int r3 = eidx[k + 3];
        float4 u0 = ((const float4*)t2s)[(size_t)r0 * 16 + f4];
        float4 u1 = ((const float4*)t2s)[(size_t)r1 * 16 + f4];
        float4 u2 = ((const float4*)t2s)[(size_t)r2 * 16 + f4];
        float4 u3 = ((const float4*)t2s)[(size_t)r3 * 16 + f4];
        acc.x += u0.x + u1.x + u2.x + u3.x;
        acc.y += u0.y + u1.y + u2.y + u3.y;
        acc.z += u0.z + u1.z + u2.z + u3.z;
        acc.w += u0.w + u1.w + u2.w + u3.w;
    }
    for (; k < k1; ++k) {
        int r = eidx[k];
        float4 u = ((const float4*)t2s)[(size_t)r * 16 + f4];
        acc.x += u.x; acc.y += u.y; acc.z += u.z; acc.w += u.w;
    }
    float dc = dinv[c];
    float4 bias = *(const float4*)&b2[f4 * 4];
    float4 o;
    o.x = fmaf(dc, acc.x, bias.x);
    o.y = fmaf(dc, acc.y, bias.y);
    o.z = fmaf(dc, acc.z, bias.z);
    o.w = fmaf(dc, acc.w, bias.w);
    ((float4*)out)[(size_t)c * 16 + f4] = o;
}

// ---------------- launch ----------------

extern "C" void kernel_launch(void* const* d_in, const int* in_sizes, int n_in,
                              void* d_out, int out_size, void* d_ws, size_t ws_size,
                              hipStream_t stream) {
    const float* x = (const float*)d_in[0];
    const int* edge_index = (const int*)d_in[1];
    const float* W1 = (const float*)d_in[2];
    const float* b1 = (const float*)d_in[3];
    const float* W2 = (const float*)d_in[4];
    const float* b2 = (const float*)d_in[5];
    float* out = (float*)d_out;

    const int* rows = edge_index;            // source nodes
    const int* cols = edge_index + N_EDGES;  // target nodes

    char* ws = (char*)d_ws;
    float* h1 = (float*)(ws);
    int* row_ptr = (int*)(ws + OFF_ROWPTR);
    int* cnt = (int*)(ws + OFF_CNT);
    int* cursor = (int*)(ws + OFF_CURSOR);
    float* dinv = (float*)(ws + OFF_DINV);
    int* eidx = (int*)(ws + OFF_EIDX);
    float* t2s = (float*)(ws + OFF_T2);

    const int BT = 256;

    // CSR build + degree norm
    zero_cnt_kernel<<<(N_NODES + BT - 1) / BT, BT, 0, stream>>>(cnt, N_NODES);
    hist_kernel<<<(N_EDGES + BT - 1) / BT, BT, 0, stream>>>(cols, cnt, N_EDGES);
    dinv_kernel<<<(N_NODES + BT - 1) / BT, BT, 0, stream>>>(cnt, dinv, N_NODES);
    scan_kernel<<<1, 1024, 0, stream>>>(cnt, row_ptr, cursor);
    scatter_kernel<<<(N_EDGES + BT - 1) / BT, BT, 0, stream>>>(rows, cols, cursor, eidx, N_EDGES);

    // layer 1: fused gather + GEMM(W1) + bias + relu
    l1_kernel<<<(N_NODES + 63) / 64, 256, 0, stream>>>(x, row_ptr, eidx, dinv, W1, b1, h1);

    // layer 2: transform (h1 @ W2, pre-scaled by dinv -> t2s), then pull-gather (+b2) into out
    {
        dim3 grid((N_NODES + 63) / 64, F_OUT / 64);
        gemm64_kernel<<<grid, 256, 0, stream>>>(h1, W2, dinv, t2s, N_NODES, F_OUT, F_HID);
    }
    l2_gather_kernel<<<(N_NODES + 15) / 16, 256, 0, stream>>>(t2s, row_ptr, eidx, dinv, b2, out);
}

// Round 10
// 386.764 us; speedup vs baseline: 5.6330x; 1.0600x over previous
//
#include <hip/hip_runtime.h>

#define N_NODES 50000
#define N_EDGES 800000
#define F_IN 128
#define F_HID 256
#define F_OUT 64

// ---------------- workspace layout (bytes) ----------------
// row_ptr @ 0.00 MiB: int[N+1]
// cnt     @ 0.25 MiB: int[N]
// cursor  @ 0.50 MiB: int[N]
// dinv    @ 0.75 MiB: f32[N]
// eidx    @ 1.00 MiB: int[E]      (3.2 MB)
// t2s     @ 4.25 MiB: [N,64] f32  (12.8 MB) -> total ~17.1 MiB

#define OFF_ROWPTR 0ull
#define OFF_CNT    (256ull << 10)
#define OFF_CURSOR (512ull << 10)
#define OFF_DINV   (768ull << 10)
#define OFF_EIDX   (1ull << 20)
#define OFF_T2     ((4ull << 20) + (256ull << 10))

// ---------------- CSR build ----------------

__global__ void zero_cnt_kernel(int* __restrict__ cnt, int n) {
    int i = blockIdx.x * blockDim.x + threadIdx.x;
    if (i < n) cnt[i] = 0;
}

__global__ void hist_kernel(const int* __restrict__ cols, int* __restrict__ cnt, int e) {
    int i = blockIdx.x * blockDim.x + threadIdx.x;
    if (i < e) atomicAdd(&cnt[cols[i]], 1);
}

__global__ void dinv_kernel(const int* __restrict__ cnt, float* __restrict__ dinv, int n) {
    int i = blockIdx.x * blockDim.x + threadIdx.x;
    if (i < n) dinv[i] = rsqrtf((float)cnt[i] + 1.0f);  // +1 self loop
}

// single-block exclusive scan of cnt -> row_ptr (and cursor copy)
__global__ __launch_bounds__(1024) void scan_kernel(const int* __restrict__ cnt,
                                                    int* __restrict__ row_ptr,
                                                    int* __restrict__ cursor) {
    __shared__ int s[1024];
    const int CH = 49;  // 1024*49 = 50176 >= 50000
    int t = threadIdx.x;
    int base = t * CH;
    int ls = 0;
    for (int i = 0; i < CH; ++i) {
        int idx = base + i;
        if (idx < N_NODES) ls += cnt[idx];
    }
    s[t] = ls;
    __syncthreads();
    for (int off = 1; off < 1024; off <<= 1) {
        int v = (t >= off) ? s[t - off] : 0;
        __syncthreads();
        s[t] += v;
        __syncthreads();
    }
    int run = s[t] - ls;  // exclusive prefix of this chunk
    for (int i = 0; i < CH; ++i) {
        int idx = base + i;
        if (idx < N_NODES) {
            row_ptr[idx] = run;
            cursor[idx] = run;
            run += cnt[idx];
        }
    }
    if (t == 0) row_ptr[N_NODES] = N_EDGES;
}

__global__ void scatter_kernel(const int* __restrict__ rows, const int* __restrict__ cols,
                               int* __restrict__ cursor, int* __restrict__ eidx, int e) {
    int i = blockIdx.x * blockDim.x + threadIdx.x;
    if (i < e) {
        int c = cols[i];
        int pos = atomicAdd(&cursor[c], 1);
        eidx[pos] = rows[i];
    }
}

// ---------------- fused layers: gather(x) -> @W1+b1+relu -> H -> @W2 (pre-scaled) -> t2s ----
// 32-node tile, 256 threads. LDS: smem 33280 B (Ax[32][128]+Bs[8][256] phase A/B;
// H[32][260] phase C) + Bs2[8][64] 2 KB = 35328 B -> 4 blocks/CU.
__global__ __launch_bounds__(256, 4) void fused12_kernel(const float* __restrict__ x,
                                                         const int* __restrict__ row_ptr,
                                                         const int* __restrict__ eidx,
                                                         const float* __restrict__ dinv,
                                                         const float* __restrict__ W1,
                                                         const float* __restrict__ b1,
                                                         const float* __restrict__ W2,
                                                         float* __restrict__ t2s) {
    __shared__ __align__(16) char smem_raw[33280];
    __shared__ float Bs2[8][64];
    float* Ax = (float*)smem_raw;                 // [32][128]
    float* Bs = (float*)(smem_raw + 16384);       // [8][256]
    float* H  = (float*)smem_raw;                 // [32][260] (padded)

    int tid = threadIdx.x;
    int bm0 = blockIdx.x * 32;

    // ---- phase A: gather, 32 lanes/node, 8 concurrent nodes, 4 passes, masked unroll-4 ----
    {
        int f4 = tid & 31;   // feature quad
        int ng = tid >> 5;   // 0..7
        for (int p = 0; p < 4; ++p) {
            int nl = p * 8 + ng;  // 0..31, 8 consecutive nodes concurrent
            int c = bm0 + nl;
            float4 acc = make_float4(0.f, 0.f, 0.f, 0.f);
            if (c < N_NODES) {
                float dc = dinv[c];
                float4 v = ((const float4*)x)[(size_t)c * 32 + f4];
                acc.x = dc * v.x; acc.y = dc * v.y; acc.z = dc * v.z; acc.w = dc * v.w;
                int k = row_ptr[c];
                int k1 = row_ptr[c + 1];
                for (; k < k1; k += 4) {
                    int i1 = (k + 1 < k1) ? k + 1 : k1 - 1;
                    int i2 = (k + 2 < k1) ? k + 2 : k1 - 1;
                    int i3 = (k + 3 < k1) ? k + 3 : k1 - 1;
                    int r0 = eidx[k];
                    int r1 = eidx[i1];
                    int r2 = eidx[i2];
                    int r3 = eidx[i3];
                    float w0 = dinv[r0];
                    float w1 = (k + 1 < k1) ? dinv[r1] : 0.f;
                    float w2 = (k + 2 < k1) ? dinv[r2] : 0.f;
                    float w3 = (k + 3 < k1) ? dinv[r3] : 0.f;
                    float4 u0 = ((const float4*)x)[(size_t)r0 * 32 + f4];
                    float4 u1 = ((const float4*)x)[(size_t)r1 * 32 + f4];
                    float4 u2 = ((const float4*)x)[(size_t)r2 * 32 + f4];
                    float4 u3 = ((const float4*)x)[(size_t)r3 * 32 + f4];
                    acc.x = fmaf(w0, u0.x, acc.x); acc.y = fmaf(w0, u0.y, acc.y);
                    acc.z = fmaf(w0, u0.z, acc.z); acc.w = fmaf(w0, u0.w, acc.w);
                    acc.x = fmaf(w1, u1.x, acc.x); acc.y = fmaf(w1, u1.y, acc.y);
                    acc.z = fmaf(w1, u1.z, acc.z); acc.w = fmaf(w1, u1.w, acc.w);
                    acc.x = fmaf(w2, u2.x, acc.x); acc.y = fmaf(w2, u2.y, acc.y);
                    acc.z = fmaf(w2, u2.z, acc.z); acc.w = fmaf(w2, u2.w, acc.w);
                    acc.x = fmaf(w3, u3.x, acc.x); acc.y = fmaf(w3, u3.y, acc.y);
                    acc.z = fmaf(w3, u3.z, acc.z); acc.w = fmaf(w3, u3.w, acc.w);
                }
                acc.x *= dc; acc.y *= dc; acc.z *= dc; acc.w *= dc;
            }
            ((float4*)&Ax[nl * 128])[f4] = acc;
        }
    }
    __syncthreads();

    // ---- phase B: C1[32x256] = Ax @ W1, +b1, relu ----
    int tx = tid & 15;   // col quad
    int ty = tid >> 4;   // 0..15 -> rows ty*2, ty*2+1
    float acc1[2][4][4] = {};  // [i][jg][q]: row=ty*2+i, col=jg*64+tx*4+q

    for (int k0 = 0; k0 < F_IN; k0 += 8) {
        {   // stage W1[k0..k0+7][0:256]
            int bk = tid >> 5;
            int c8 = tid & 31;
            const float4* src = (const float4*)&W1[(size_t)(k0 + bk) * F_HID + c8 * 8];
            float4 u0 = src[0];
            float4 u1 = src[1];
            ((float4*)&Bs[bk * 256 + c8 * 8])[0] = u0;
            ((float4*)&Bs[bk * 256 + c8 * 8])[1] = u1;
        }
        __syncthreads();
#pragma unroll
        for (int kk4 = 0; kk4 < 2; ++kk4) {
            float4 a4[2];
#pragma unroll
            for (int i = 0; i < 2; ++i)
                a4[i] = *(const float4*)&Ax[(ty * 2 + i) * 128 + k0 + kk4 * 4];
#pragma unroll
            for (int q4 = 0; q4 < 4; ++q4) {
                int kk = kk4 * 4 + q4;
                float a[2];
                a[0] = (q4 == 0) ? a4[0].x : (q4 == 1) ? a4[0].y : (q4 == 2) ? a4[0].z : a4[0].w;
                a[1] = (q4 == 0) ? a4[1].x : (q4 == 1) ? a4[1].y : (q4 == 2) ? a4[1].z : a4[1].w;
                float b[4][4];
#pragma unroll
                for (int jg = 0; jg < 4; ++jg) {
                    float4 bb = *(const float4*)&Bs[kk * 256 + jg * 64 + tx * 4];
                    b[jg][0] = bb.x; b[jg][1] = bb.y; b[jg][2] = bb.z; b[jg][3] = bb.w;
                }
#pragma unroll
                for (int i = 0; i < 2; ++i)
#pragma unroll
                    for (int jg = 0; jg < 4; ++jg)
#pragma unroll
                        for (int q = 0; q < 4; ++q)
                            acc1[i][jg][q] = fmaf(a[i], b[jg][q], acc1[i][jg][q]);
            }
        }
        __syncthreads();
    }

    // ---- write H (aliases Ax/Bs; all Ax reads done at last sync) ----
#pragma unroll
    for (int i = 0; i < 2; ++i) {
#pragma unroll
        for (int jg = 0; jg < 4; ++jg) {
            int col = jg * 64 + tx * 4;
            float4 bias = *(const float4*)&b1[col];
            float4 o;
            o.x = fmaxf(acc1[i][jg][0] + bias.x, 0.f);
            o.y = fmaxf(acc1[i][jg][1] + bias.y, 0.f);
            o.z = fmaxf(acc1[i][jg][2] + bias.z, 0.f);
            o.w = fmaxf(acc1[i][jg][3] + bias.w, 0.f);
            *(float4*)&H[(ty * 2 + i) * 260 + col] = o;
        }
    }

    // ---- phase C: t2s[32x64] = dinv * (H @ W2) ----
    float acc2[2][4] = {};  // row=ty*2+i, col=tx*4+q
    for (int k0 = 0; k0 < F_HID; k0 += 8) {
        {   // stage W2[k0..k0+7][0:64]
            int bk = tid >> 5;
            int c2 = (tid & 31) * 2;
            *(float2*)&Bs2[bk][c2] = *(const float2*)&W2[(size_t)(k0 + bk) * F_OUT + c2];
        }
        __syncthreads();
#pragma unroll
        for (int kk = 0; kk < 8; ++kk) {
            float a0 = H[(ty * 2 + 0) * 260 + k0 + kk];
            float a1 = H[(ty * 2 + 1) * 260 + k0 + kk];
            float4 bb = *(const float4*)&Bs2[kk][tx * 4];
            acc2[0][0] = fmaf(a0, bb.x, acc2[0][0]);
            acc2[0][1] = fmaf(a0, bb.y, acc2[0][1]);
            acc2[0][2] = fmaf(a0, bb.z, acc2[0][2]);
            acc2[0][3] = fmaf(a0, bb.w, acc2[0][3]);
            acc2[1][0] = fmaf(a1, bb.x, acc2[1][0]);
            acc2[1][1] = fmaf(a1, bb.y, acc2[1][1]);
            acc2[1][2] = fmaf(a1, bb.z, acc2[1][2]);
            acc2[1][3] = fmaf(a1, bb.w, acc2[1][3]);
        }
        __syncthreads();
    }

#pragma unroll
    for (int i = 0; i < 2; ++i) {
        int row = bm0 + ty * 2 + i;
        if (row >= N_NODES) continue;
        float d = dinv[row];
        float4 o;
        o.x = d * acc2[i][0];
        o.y = d * acc2[i][1];
        o.z = d * acc2[i][2];
        o.w = d * acc2[i][3];
        *(float4*)&t2s[(size_t)row * F_OUT + tx * 4] = o;
    }
}

// ---------------- layer 2 pull-gather: out = dinv[c]*(t2s[c] + sum t2s[r]) + b2 ----------------
// 16 nodes/block, 16 lanes (float4 each) per node. t2s is pre-scaled by dinv. Masked unroll-4.
__global__ __launch_bounds__(256) void l2_gather_kernel(const float* __restrict__ t2s,
                                                        const int* __restrict__ row_ptr,
                                                        const int* __restrict__ eidx,
                                                        const float* __restrict__ dinv,
                                                        const float* __restrict__ b2,
                                                        float* __restrict__ out) {
    int tid = threadIdx.x;
    int f4 = tid & 15;   // feature quad (64 feats)
    int nl = tid >> 4;   // 0..15
    int c = blockIdx.x * 16 + nl;
    if (c >= N_NODES) return;
    float4 acc = ((const float4*)t2s)[(size_t)c * 16 + f4];  // self loop (pre-scaled)
    int k = row_ptr[c];
    int k1 = row_ptr[c + 1];
    for (; k < k1; k += 4) {
        int i1 = (k + 1 < k1) ? k + 1 : k1 - 1;
        int i2 = (k + 2 < k1) ? k + 2 : k1 - 1;
        int i3 = (k + 3 < k1) ? k + 3 : k1 - 1;
        int r0 = eidx[k];
        int r1 = eidx[i1];
        int r2 = eidx[i2];
        int r3 = eidx[i3];
        float m1 = (k + 1 < k1) ? 1.f : 0.f;
        float m2 = (k + 2 < k1) ? 1.f : 0.f;
        float m3 = (k + 3 < k1) ? 1.f : 0.f;
        float4 u0 = ((const float4*)t2s)[(size_t)r0 * 16 + f4];
        float4 u1 = ((const float4*)t2s)[(size_t)r1 * 16 + f4];
        float4 u2 = ((const float4*)t2s)[(size_t)r2 * 16 + f4];
        float4 u3 = ((const float4*)t2s)[(size_t)r3 * 16 + f4];
        acc.x += u0.x; acc.y += u0.y; acc.z += u0.z; acc.w += u0.w;
        acc.x = fmaf(m1, u1.x, acc.x); acc.y = fmaf(m1, u1.y, acc.y);
        acc.z = fmaf(m1, u1.z, acc.z); acc.w = fmaf(m1, u1.w, acc.w);
        acc.x = fmaf(m2, u2.x, acc.x); acc.y = fmaf(m2, u2.y, acc.y);
        acc.z = fmaf(m2, u2.z, acc.z); acc.w = fmaf(m2, u2.w, acc.w);
        acc.x = fmaf(m3, u3.x, acc.x); acc.y = fmaf(m3, u3.y, acc.y);
        acc.z = fmaf(m3, u3.z, acc.z); acc.w = fmaf(m3, u3.w, acc.w);
    }
    float dc = dinv[c];
    float4 bias = *(const float4*)&b2[f4 * 4];
    float4 o;
    o.x = fmaf(dc, acc.x, bias.x);
    o.y = fmaf(dc, acc.y, bias.y);
    o.z = fmaf(dc, acc.z, bias.z);
    o.w = fmaf(dc, acc.w, bias.w);
    ((float4*)out)[(size_t)c * 16 + f4] = o;
}

// ---------------- launch ----------------

extern "C" void kernel_launch(void* const* d_in, const int* in_sizes, int n_in,
                              void* d_out, int out_size, void* d_ws, size_t ws_size,
                              hipStream_t stream) {
    const float* x = (const float*)d_in[0];
    const int* edge_index = (const int*)d_in[1];
    const float* W1 = (const float*)d_in[2];
    const float* b1 = (const float*)d_in[3];
    const float* W2 = (const float*)d_in[4];
    const float* b2 = (const float*)d_in[5];
    float* out = (float*)d_out;

    const int* rows = edge_index;            // source nodes
    const int* cols = edge_index + N_EDGES;  // target nodes

    char* ws = (char*)d_ws;
    int* row_ptr = (int*)(ws + OFF_ROWPTR);
    int* cnt = (int*)(ws + OFF_CNT);
    int* cursor = (int*)(ws + OFF_CURSOR);
    float* dinv = (float*)(ws + OFF_DINV);
    int* eidx = (int*)(ws + OFF_EIDX);
    float* t2s = (float*)(ws + OFF_T2);

    const int BT = 256;

    // CSR build + degree norm
    zero_cnt_kernel<<<(N_NODES + BT - 1) / BT, BT, 0, stream>>>(cnt, N_NODES);
    hist_kernel<<<(N_EDGES + BT - 1) / BT, BT, 0, stream>>>(cols, cnt, N_EDGES);
    dinv_kernel<<<(N_NODES + BT - 1) / BT, BT, 0, stream>>>(cnt, dinv, N_NODES);
    scan_kernel<<<1, 1024, 0, stream>>>(cnt, row_ptr, cursor);
    scatter_kernel<<<(N_EDGES + BT - 1) / BT, BT, 0, stream>>>(rows, cols, cursor, eidx, N_EDGES);

    // fused: gather + @W1+b1+relu + @W2 (pre-scaled by dinv) -> t2s
    fused12_kernel<<<(N_NODES + 31) / 32, 256, 0, stream>>>(x, row_ptr, eidx, dinv, W1, b1, W2, t2s);

    // layer 2 propagate (+b2) into out
    l2_gather_kernel<<<(N_NODES + 15) / 16, 256, 0, stream>>>(t2s, row_ptr, eidx, dinv, b2, out);
}

// Round 11
// 355.890 us; speedup vs baseline: 6.1217x; 1.0867x over previous
//
#include <hip/hip_runtime.h>

#define N_NODES 50000
#define N_EDGES 800000
#define F_IN 128
#define F_HID 256
#define F_OUT 64

// ---------------- workspace layout (bytes) ----------------
// row_ptr @ 0.00 MiB: int[N+1]
// cnt     @ 0.25 MiB: int[N]
// cursor  @ 0.50 MiB: int[N]
// dinv    @ 0.75 MiB: f32[N]
// eidx    @ 1.00 MiB: int[E]          (3.2 MB)
// xb      @ 4.25 MiB: bf16[N,128]     (12.8 MB)
// t2b     @ 17.5 MiB: bf16[N,64]      (6.4 MB)   -> total ~23.9 MiB

#define OFF_ROWPTR 0ull
#define OFF_CNT    (256ull << 10)
#define OFF_CURSOR (512ull << 10)
#define OFF_DINV   (768ull << 10)
#define OFF_EIDX   (1ull << 20)
#define OFF_XB     ((4ull << 20) + (256ull << 10))
#define OFF_T2B    ((17ull << 20) + (512ull << 10))

// ---------------- bf16 helpers ----------------

__device__ __forceinline__ unsigned f2bf(float f) {  // RNE to bf16 (low 16 bits)
    unsigned u = __float_as_uint(f);
    return (u + 0x7FFFu + ((u >> 16) & 1u)) >> 16;
}
__device__ __forceinline__ float bflo(unsigned u) { return __uint_as_float(u << 16); }
__device__ __forceinline__ float bfhi(unsigned u) { return __uint_as_float(u & 0xFFFF0000u); }

// ---------------- x -> bf16 conversion ----------------

__global__ void cvt_kernel(const float* __restrict__ x, unsigned* __restrict__ xb) {
    int i = blockIdx.x * blockDim.x + threadIdx.x;  // each handles 8 floats
    if (i >= N_NODES * (F_IN / 8)) return;
    float4 a = ((const float4*)x)[(size_t)i * 2];
    float4 b = ((const float4*)x)[(size_t)i * 2 + 1];
    uint4 o;
    o.x = f2bf(a.x) | (f2bf(a.y) << 16);
    o.y = f2bf(a.z) | (f2bf(a.w) << 16);
    o.z = f2bf(b.x) | (f2bf(b.y) << 16);
    o.w = f2bf(b.z) | (f2bf(b.w) << 16);
    ((uint4*)xb)[i] = o;
}

// ---------------- CSR build ----------------

__global__ void zero_cnt_kernel(int* __restrict__ cnt, int n) {
    int i = blockIdx.x * blockDim.x + threadIdx.x;
    if (i < n) cnt[i] = 0;
}

__global__ void hist_kernel(const int* __restrict__ cols, int* __restrict__ cnt, int e) {
    int i = blockIdx.x * blockDim.x + threadIdx.x;
    if (i < e) atomicAdd(&cnt[cols[i]], 1);
}

__global__ void dinv_kernel(const int* __restrict__ cnt, float* __restrict__ dinv, int n) {
    int i = blockIdx.x * blockDim.x + threadIdx.x;
    if (i < n) dinv[i] = rsqrtf((float)cnt[i] + 1.0f);  // +1 self loop
}

__global__ __launch_bounds__(1024) void scan_kernel(const int* __restrict__ cnt,
                                                    int* __restrict__ row_ptr,
                                                    int* __restrict__ cursor) {
    __shared__ int s[1024];
    const int CH = 49;
    int t = threadIdx.x;
    int base = t * CH;
    int ls = 0;
    for (int i = 0; i < CH; ++i) {
        int idx = base + i;
        if (idx < N_NODES) ls += cnt[idx];
    }
    s[t] = ls;
    __syncthreads();
    for (int off = 1; off < 1024; off <<= 1) {
        int v = (t >= off) ? s[t - off] : 0;
        __syncthreads();
        s[t] += v;
        __syncthreads();
    }
    int run = s[t] - ls;
    for (int i = 0; i < CH; ++i) {
        int idx = base + i;
        if (idx < N_NODES) {
            row_ptr[idx] = run;
            cursor[idx] = run;
            run += cnt[idx];
        }
    }
    if (t == 0) row_ptr[N_NODES] = N_EDGES;
}

__global__ void scatter_kernel(const int* __restrict__ rows, const int* __restrict__ cols,
                               int* __restrict__ cursor, int* __restrict__ eidx, int e) {
    int i = blockIdx.x * blockDim.x + threadIdx.x;
    if (i < e) {
        int c = cols[i];
        int pos = atomicAdd(&cursor[c], 1);
        eidx[pos] = rows[i];
    }
}

// ---------------- fused: bf16-gather -> @W1+b1+relu -> Hchunk -> @W2 -> t2b ----------------
// 32-node tile, 256 threads. LDS 24576 B: Ax[32][128]f32 (16K) + Bs[8][256] (8K);
// phase C Hchunk[32][66] (8.4K) aliases Ax. Target 6 blocks/CU.
__global__ __launch_bounds__(256, 4) void fused12_kernel(const unsigned* __restrict__ xb,
                                                         const int* __restrict__ row_ptr,
                                                         const int* __restrict__ eidx,
                                                         const float* __restrict__ dinv,
                                                         const float* __restrict__ W1,
                                                         const float* __restrict__ b1,
                                                         const float* __restrict__ W2,
                                                         unsigned* __restrict__ t2b) {
    __shared__ __align__(16) char smem_raw[24576];
    float* Ax = (float*)smem_raw;              // [32][128]
    float* Bs = (float*)(smem_raw + 16384);    // [8][256]
    float* Hc = (float*)smem_raw;              // [32][66] (phase C chunk, aliases Ax)

    int tid = threadIdx.x;
    int bm0 = blockIdx.x * 32;

    // ---- phase A: bf16 gather. 16 lanes/node (8 bf16 each), 16 nodes concurrent, 2 passes ----
    {
        int f8 = tid & 15;   // feature octet: feats f8*8..f8*8+7
        int ng = tid >> 4;   // 0..15
        for (int p = 0; p < 2; ++p) {
            int nl = p * 16 + ng;  // 0..31
            int c = bm0 + nl;
            float acc[8] = {};
            if (c < N_NODES) {
                float dc = dinv[c];
                uint4 S = ((const uint4*)xb)[(size_t)c * 16 + f8];
                acc[0] = dc * bflo(S.x); acc[1] = dc * bfhi(S.x);
                acc[2] = dc * bflo(S.y); acc[3] = dc * bfhi(S.y);
                acc[4] = dc * bflo(S.z); acc[5] = dc * bfhi(S.z);
                acc[6] = dc * bflo(S.w); acc[7] = dc * bfhi(S.w);
                int k = row_ptr[c];
                int k1 = row_ptr[c + 1];
                for (; k < k1; k += 4) {
                    int i1 = (k + 1 < k1) ? k + 1 : k1 - 1;
                    int i2 = (k + 2 < k1) ? k + 2 : k1 - 1;
                    int i3 = (k + 3 < k1) ? k + 3 : k1 - 1;
                    int r0 = eidx[k];
                    int r1 = eidx[i1];
                    int r2 = eidx[i2];
                    int r3 = eidx[i3];
                    float w0 = dinv[r0];
                    float w1 = (k + 1 < k1) ? dinv[r1] : 0.f;
                    float w2 = (k + 2 < k1) ? dinv[r2] : 0.f;
                    float w3 = (k + 3 < k1) ? dinv[r3] : 0.f;
                    uint4 U0 = ((const uint4*)xb)[(size_t)r0 * 16 + f8];
                    uint4 U1 = ((const uint4*)xb)[(size_t)r1 * 16 + f8];
                    uint4 U2 = ((const uint4*)xb)[(size_t)r2 * 16 + f8];
                    uint4 U3 = ((const uint4*)xb)[(size_t)r3 * 16 + f8];
                    acc[0] = fmaf(w0, bflo(U0.x), acc[0]); acc[1] = fmaf(w0, bfhi(U0.x), acc[1]);
                    acc[2] = fmaf(w0, bflo(U0.y), acc[2]); acc[3] = fmaf(w0, bfhi(U0.y), acc[3]);
                    acc[4] = fmaf(w0, bflo(U0.z), acc[4]); acc[5] = fmaf(w0, bfhi(U0.z), acc[5]);
                    acc[6] = fmaf(w0, bflo(U0.w), acc[6]); acc[7] = fmaf(w0, bfhi(U0.w), acc[7]);
                    acc[0] = fmaf(w1, bflo(U1.x), acc[0]); acc[1] = fmaf(w1, bfhi(U1.x), acc[1]);
                    acc[2] = fmaf(w1, bflo(U1.y), acc[2]); acc[3] = fmaf(w1, bfhi(U1.y), acc[3]);
                    acc[4] = fmaf(w1, bflo(U1.z), acc[4]); acc[5] = fmaf(w1, bfhi(U1.z), acc[5]);
                    acc[6] = fmaf(w1, bflo(U1.w), acc[6]); acc[7] = fmaf(w1, bfhi(U1.w), acc[7]);
                    acc[0] = fmaf(w2, bflo(U2.x), acc[0]); acc[1] = fmaf(w2, bfhi(U2.x), acc[1]);
                    acc[2] = fmaf(w2, bflo(U2.y), acc[2]); acc[3] = fmaf(w2, bfhi(U2.y), acc[3]);
                    acc[4] = fmaf(w2, bflo(U2.z), acc[4]); acc[5] = fmaf(w2, bfhi(U2.z), acc[5]);
                    acc[6] = fmaf(w2, bflo(U2.w), acc[6]); acc[7] = fmaf(w2, bfhi(U2.w), acc[7]);
                    acc[0] = fmaf(w3, bflo(U3.x), acc[0]); acc[1] = fmaf(w3, bfhi(U3.x), acc[1]);
                    acc[2] = fmaf(w3, bflo(U3.y), acc[2]); acc[3] = fmaf(w3, bfhi(U3.y), acc[3]);
                    acc[4] = fmaf(w3, bflo(U3.z), acc[4]); acc[5] = fmaf(w3, bfhi(U3.z), acc[5]);
                    acc[6] = fmaf(w3, bflo(U3.w), acc[6]); acc[7] = fmaf(w3, bfhi(U3.w), acc[7]);
                }
#pragma unroll
                for (int q = 0; q < 8; ++q) acc[q] *= dc;
            }
            float4 o0 = make_float4(acc[0], acc[1], acc[2], acc[3]);
            float4 o1 = make_float4(acc[4], acc[5], acc[6], acc[7]);
            *(float4*)&Ax[nl * 128 + f8 * 8] = o0;
            *(float4*)&Ax[nl * 128 + f8 * 8 + 4] = o1;
        }
    }
    __syncthreads();

    // ---- phase B: acc1[32x256] = Ax @ W1 ----
    int tx = tid & 15;   // col quad
    int ty = tid >> 4;   // 0..15 -> rows ty*2, ty*2+1
    float acc1[2][4][4] = {};  // [i][jg][q]: row=ty*2+i, col=jg*64+tx*4+q

    for (int k0 = 0; k0 < F_IN; k0 += 8) {
        {   // stage W1[k0..k0+7][0:256]
            int bk = tid >> 5;
            int c8 = tid & 31;
            const float4* src = (const float4*)&W1[(size_t)(k0 + bk) * F_HID + c8 * 8];
            float4 u0 = src[0];
            float4 u1 = src[1];
            ((float4*)&Bs[bk * 256 + c8 * 8])[0] = u0;
            ((float4*)&Bs[bk * 256 + c8 * 8])[1] = u1;
        }
        __syncthreads();
#pragma unroll
        for (int kk4 = 0; kk4 < 2; ++kk4) {
            float4 a4[2];
#pragma unroll
            for (int i = 0; i < 2; ++i)
                a4[i] = *(const float4*)&Ax[(ty * 2 + i) * 128 + k0 + kk4 * 4];
#pragma unroll
            for (int q4 = 0; q4 < 4; ++q4) {
                int kk = kk4 * 4 + q4;
                float a[2];
                a[0] = (q4 == 0) ? a4[0].x : (q4 == 1) ? a4[0].y : (q4 == 2) ? a4[0].z : a4[0].w;
                a[1] = (q4 == 0) ? a4[1].x : (q4 == 1) ? a4[1].y : (q4 == 2) ? a4[1].z : a4[1].w;
                float b[4][4];
#pragma unroll
                for (int jg = 0; jg < 4; ++jg) {
                    float4 bb = *(const float4*)&Bs[kk * 256 + jg * 64 + tx * 4];
                    b[jg][0] = bb.x; b[jg][1] = bb.y; b[jg][2] = bb.z; b[jg][3] = bb.w;
                }
#pragma unroll
                for (int i = 0; i < 2; ++i)
#pragma unroll
                    for (int jg = 0; jg < 4; ++jg)
#pragma unroll
                        for (int q = 0; q < 4; ++q)
                            acc1[i][jg][q] = fmaf(a[i], b[jg][q], acc1[i][jg][q]);
            }
        }
        __syncthreads();
    }

    // ---- phase C: chunked H (64 cols at a time) -> acc2 += Hc @ W2chunk ----
    float acc2[2][4] = {};  // row=ty*2+i, col=tx*4+q
#pragma unroll
    for (int jg = 0; jg < 4; ++jg) {
        // write H chunk (bias+relu) into Hc[32][66]
#pragma unroll
        for (int i = 0; i < 2; ++i) {
            int col = jg * 64 + tx * 4;
            float4 bias = *(const float4*)&b1[col];
            Hc[(ty * 2 + i) * 66 + tx * 4 + 0] = fmaxf(acc1[i][jg][0] + bias.x, 0.f);
            Hc[(ty * 2 + i) * 66 + tx * 4 + 1] = fmaxf(acc1[i][jg][1] + bias.y, 0.f);
            Hc[(ty * 2 + i) * 66 + tx * 4 + 2] = fmaxf(acc1[i][jg][2] + bias.z, 0.f);
            Hc[(ty * 2 + i) * 66 + tx * 4 + 3] = fmaxf(acc1[i][jg][3] + bias.w, 0.f);
        }
        __syncthreads();
        const float4* W2r = (const float4*)W2;
#pragma unroll 8
        for (int k = 0; k < 64; ++k) {
            float a0 = Hc[(ty * 2 + 0) * 66 + k];
            float a1 = Hc[(ty * 2 + 1) * 66 + k];
            float4 bb = W2r[(size_t)(jg * 64 + k) * 16 + tx];
            acc2[0][0] = fmaf(a0, bb.x, acc2[0][0]);
            acc2[0][1] = fmaf(a0, bb.y, acc2[0][1]);
            acc2[0][2] = fmaf(a0, bb.z, acc2[0][2]);
            acc2[0][3] = fmaf(a0, bb.w, acc2[0][3]);
            acc2[1][0] = fmaf(a1, bb.x, acc2[1][0]);
            acc2[1][1] = fmaf(a1, bb.y, acc2[1][1]);
            acc2[1][2] = fmaf(a1, bb.z, acc2[1][2]);
            acc2[1][3] = fmaf(a1, bb.w, acc2[1][3]);
        }
        __syncthreads();
    }

    // ---- write t2b = bf16(dinv * acc2) ----
#pragma unroll
    for (int i = 0; i < 2; ++i) {
        int row = bm0 + ty * 2 + i;
        if (row >= N_NODES) continue;
        float d = dinv[row];
        uint2 o;
        o.x = f2bf(d * acc2[i][0]) | (f2bf(d * acc2[i][1]) << 16);
        o.y = f2bf(d * acc2[i][2]) | (f2bf(d * acc2[i][3]) << 16);
        *(uint2*)((unsigned short*)t2b + (size_t)row * 64 + tx * 4) = o;
    }
}

// ---------------- layer 2 pull-gather (bf16): out = dinv[c]*(t2b[c] + sum t2b[r]) + b2 ----
// 32 nodes/block, 8 lanes (8 bf16 each) per node. t2b pre-scaled by dinv. Masked unroll-4.
__global__ __launch_bounds__(256) void l2_gather_kernel(const unsigned* __restrict__ t2b,
                                                        const int* __restrict__ row_ptr,
                                                        const int* __restrict__ eidx,
                                                        const float* __restrict__ dinv,
                                                        const float* __restrict__ b2,
                                                        float* __restrict__ out) {
    int tid = threadIdx.x;
    int f8 = tid & 7;    // feature octet (64 feats)
    int nl = tid >> 3;   // 0..31
    int c = blockIdx.x * 32 + nl;
    if (c >= N_NODES) return;
    uint4 S = ((const uint4*)t2b)[(size_t)c * 8 + f8];  // self (pre-scaled)
    float acc[8];
    acc[0] = bflo(S.x); acc[1] = bfhi(S.x);
    acc[2] = bflo(S.y); acc[3] = bfhi(S.y);
    acc[4] = bflo(S.z); acc[5] = bfhi(S.z);
    acc[6] = bflo(S.w); acc[7] = bfhi(S.w);
    int k = row_ptr[c];
    int k1 = row_ptr[c + 1];
    for (; k < k1; k += 4) {
        int i1 = (k + 1 < k1) ? k + 1 : k1 - 1;
        int i2 = (k + 2 < k1) ? k + 2 : k1 - 1;
        int i3 = (k + 3 < k1) ? k + 3 : k1 - 1;
        int r0 = eidx[k];
        int r1 = eidx[i1];
        int r2 = eidx[i2];
        int r3 = eidx[i3];
        float m1 = (k + 1 < k1) ? 1.f : 0.f;
        float m2 = (k + 2 < k1) ? 1.f : 0.f;
        float m3 = (k + 3 < k1) ? 1.f : 0.f;
        uint4 U0 = ((const uint4*)t2b)[(size_t)r0 * 8 + f8];
        uint4 U1 = ((const uint4*)t2b)[(size_t)r1 * 8 + f8];
        uint4 U2 = ((const uint4*)t2b)[(size_t)r2 * 8 + f8];
        uint4 U3 = ((const uint4*)t2b)[(size_t)r3 * 8 + f8];
        acc[0] += bflo(U0.x); acc[1] += bfhi(U0.x);
        acc[2] += bflo(U0.y); acc[3] += bfhi(U0.y);
        acc[4] += bflo(U0.z); acc[5] += bfhi(U0.z);
        acc[6] += bflo(U0.w); acc[7] += bfhi(U0.w);
        acc[0] = fmaf(m1, bflo(U1.x), acc[0]); acc[1] = fmaf(m1, bfhi(U1.x), acc[1]);
        acc[2] = fmaf(m1, bflo(U1.y), acc[2]); acc[3] = fmaf(m1, bfhi(U1.y), acc[3]);
        acc[4] = fmaf(m1, bflo(U1.z), acc[4]); acc[5] = fmaf(m1, bfhi(U1.z), acc[5]);
        acc[6] = fmaf(m1, bflo(U1.w), acc[6]); acc[7] = fmaf(m1, bfhi(U1.w), acc[7]);
        acc[0] = fmaf(m2, bflo(U2.x), acc[0]); acc[1] = fmaf(m2, bfhi(U2.x), acc[1]);
        acc[2] = fmaf(m2, bflo(U2.y), acc[2]); acc[3] = fmaf(m2, bfhi(U2.y), acc[3]);
        acc[4] = fmaf(m2, bflo(U2.z), acc[4]); acc[5] = fmaf(m2, bfhi(U2.z), acc[5]);
        acc[6] = fmaf(m2, bflo(U2.w), acc[6]); acc[7] = fmaf(m2, bfhi(U2.w), acc[7]);
        acc[0] = fmaf(m3, bflo(U3.x), acc[0]); acc[1] = fmaf(m3, bfhi(U3.x), acc[1]);
        acc[2] = fmaf(m3, bflo(U3.y), acc[2]); acc[3] = fmaf(m3, bfhi(U3.y), acc[3]);
        acc[4] = fmaf(m3, bflo(U3.z), acc[4]); acc[5] = fmaf(m3, bfhi(U3.z), acc[5]);
        acc[6] = fmaf(m3, bflo(U3.w), acc[6]); acc[7] = fmaf(m3, bfhi(U3.w), acc[7]);
    }
    float dc = dinv[c];
    float4 b2a = *(const float4*)&b2[f8 * 8];
    float4 b2b = *(const float4*)&b2[f8 * 8 + 4];
    float4 o0, o1;
    o0.x = fmaf(dc, acc[0], b2a.x);
    o0.y = fmaf(dc, acc[1], b2a.y);
    o0.z = fmaf(dc, acc[2], b2a.z);
    o0.w = fmaf(dc, acc[3], b2a.w);
    o1.x = fmaf(dc, acc[4], b2b.x);
    o1.y = fmaf(dc, acc[5], b2b.y);
    o1.z = fmaf(dc, acc[6], b2b.z);
    o1.w = fmaf(dc, acc[7], b2b.w);
    ((float4*)out)[(size_t)c * 16 + f8 * 2] = o0;
    ((float4*)out)[(size_t)c * 16 + f8 * 2 + 1] = o1;
}

// ---------------- launch ----------------

extern "C" void kernel_launch(void* const* d_in, const int* in_sizes, int n_in,
                              void* d_out, int out_size, void* d_ws, size_t ws_size,
                              hipStream_t stream) {
    const float* x = (const float*)d_in[0];
    const int* edge_index = (const int*)d_in[1];
    const float* W1 = (const float*)d_in[2];
    const float* b1 = (const float*)d_in[3];
    const float* W2 = (const float*)d_in[4];
    const float* b2 = (const float*)d_in[5];
    float* out = (float*)d_out;

    const int* rows = edge_index;            // source nodes
    const int* cols = edge_index + N_EDGES;  // target nodes

    char* ws = (char*)d_ws;
    int* row_ptr = (int*)(ws + OFF_ROWPTR);
    int* cnt = (int*)(ws + OFF_CNT);
    int* cursor = (int*)(ws + OFF_CURSOR);
    float* dinv = (float*)(ws + OFF_DINV);
    int* eidx = (int*)(ws + OFF_EIDX);
    unsigned* xb = (unsigned*)(ws + OFF_XB);
    unsigned* t2b = (unsigned*)(ws + OFF_T2B);

    const int BT = 256;

    // x -> bf16 (independent of CSR build)
    cvt_kernel<<<(N_NODES * (F_IN / 8) + BT - 1) / BT, BT, 0, stream>>>(x, xb);

    // CSR build + degree norm
    zero_cnt_kernel<<<(N_NODES + BT - 1) / BT, BT, 0, stream>>>(cnt, N_NODES);
    hist_kernel<<<(N_EDGES + BT - 1) / BT, BT, 0, stream>>>(cols, cnt, N_EDGES);
    dinv_kernel<<<(N_NODES + BT - 1) / BT, BT, 0, stream>>>(cnt, dinv, N_NODES);
    scan_kernel<<<1, 1024, 0, stream>>>(cnt, row_ptr, cursor);
    scatter_kernel<<<(N_EDGES + BT - 1) / BT, BT, 0, stream>>>(rows, cols, cursor, eidx, N_EDGES);

    // fused: bf16 gather + @W1+b1+relu + @W2 (pre-scaled by dinv) -> t2b (bf16)
    fused12_kernel<<<(N_NODES + 31) / 32, 256, 0, stream>>>(xb, row_ptr, eidx, dinv, W1, b1, W2, t2b);

    // layer 2 propagate (+b2) into out (fp32)
    l2_gather_kernel<<<(N_NODES + 31) / 32, 256, 0, stream>>>(t2b, row_ptr, eidx, dinv, b2, out);
}